// Round 1
// baseline (211.084 us; speedup 1.0000x reference)
//
#include <hip/hip_runtime.h>
#include <math.h>

#define M_ 3
#define B_ 64
#define D_ 512
#define H4 128     // D/4
#define HIST_ 5

__device__ __forceinline__ float wave_sum64(float v) {
#pragma unroll
    for (int o = 32; o >= 1; o >>= 1) v += __shfl_xor(v, o, 64);
    return v;
}

__device__ __forceinline__ float sigmoidf(float x) {
    return 1.0f / (1.0f + __expf(-x));
}

// ---------------------------------------------------------------------------
// Kernel 1: per (mode, batch-row) — proj GEMV + LayerNorm + ReLU, importance
// MLP, wf = proj * sigmoid(...), and S[m,b] = sum_e wf.
// grid = M_*B_ = 192 blocks, 256 threads.
// ---------------------------------------------------------------------------
__global__ __launch_bounds__(256) void k_wf(
    const float* __restrict__ x,  const float* __restrict__ pW,
    const float* __restrict__ pb, const float* __restrict__ lg,
    const float* __restrict__ lb, const float* __restrict__ W1,
    const float* __restrict__ b1, const float* __restrict__ W2,
    const float* __restrict__ b2, float* __restrict__ wf,
    float* __restrict__ Ssum)
{
    const int m = blockIdx.x >> 6;
    const int b = blockIdx.x & 63;
    const int t = threadIdx.x;
    __shared__ __align__(16) float xs[D_];
    __shared__ __align__(16) float ps[D_];
    __shared__ __align__(16) float hs[H4];
    __shared__ float red[8];

    const float* xrow = x + (size_t)(m * B_ + b) * D_;
    xs[t] = xrow[t];
    xs[t + 256] = xrow[t + 256];
    __syncthreads();

    // y[d] = x[b,:] . W[d,:] + pb[d], for d = t and t+256
    float y[2];
    const float* Wm = pW + (size_t)m * D_ * D_;
#pragma unroll
    for (int r = 0; r < 2; ++r) {
        const int d = t + (r << 8);
        const float4* wr = (const float4*)(Wm + (size_t)d * D_);
        const float4* xv = (const float4*)xs;
        float acc = 0.f;
#pragma unroll 8
        for (int k = 0; k < D_ / 4; ++k) {
            float4 w = wr[k], xx = xv[k];
            acc = fmaf(w.x, xx.x, acc); acc = fmaf(w.y, xx.y, acc);
            acc = fmaf(w.z, xx.z, acc); acc = fmaf(w.w, xx.w, acc);
        }
        y[r] = acc + pb[m * D_ + d];
    }

    // LayerNorm over 512 (2 per thread, 4 waves)
    float s = wave_sum64(y[0] + y[1]);
    if ((t & 63) == 0) red[t >> 6] = s;
    __syncthreads();
    const float mean = (red[0] + red[1] + red[2] + red[3]) * (1.f / D_);
    const float v0 = y[0] - mean, v1 = y[1] - mean;
    float vs = wave_sum64(v0 * v0 + v1 * v1);
    if ((t & 63) == 0) red[4 + (t >> 6)] = vs;
    __syncthreads();
    const float inv = rsqrtf((red[4] + red[5] + red[6] + red[7]) * (1.f / D_) + 1e-5f);
    const float p0 = fmaxf(fmaf(v0 * inv, lg[m * D_ + t],       lb[m * D_ + t]),       0.f);
    const float p1 = fmaxf(fmaf(v1 * inv, lg[m * D_ + t + 256], lb[m * D_ + t + 256]), 0.f);
    ps[t] = p0;
    ps[t + 256] = p1;
    __syncthreads();

    // h = relu(proj @ W1^T + b1)  [128]
    if (t < H4) {
        const float4* w1 = (const float4*)(W1 + (size_t)(m * H4 + t) * D_);
        const float4* pv = (const float4*)ps;
        float acc = 0.f;
#pragma unroll 8
        for (int k = 0; k < D_ / 4; ++k) {
            float4 w = w1[k], pp = pv[k];
            acc = fmaf(w.x, pp.x, acc); acc = fmaf(w.y, pp.y, acc);
            acc = fmaf(w.z, pp.z, acc); acc = fmaf(w.w, pp.w, acc);
        }
        hs[t] = fmaxf(acc + b1[m * H4 + t], 0.f);
    }
    __syncthreads();

    // cw = sigmoid(h @ W2^T + b2); wf = proj * cw; S = sum(wf)
    float wsum = 0.f;
#pragma unroll
    for (int r = 0; r < 2; ++r) {
        const int d = t + (r << 8);
        const float4* w2 = (const float4*)(W2 + (size_t)(m * D_ + d) * H4);
        const float4* hv = (const float4*)hs;
        float acc = 0.f;
#pragma unroll 8
        for (int k = 0; k < H4 / 4; ++k) {
            float4 w = w2[k], hh = hv[k];
            acc = fmaf(w.x, hh.x, acc); acc = fmaf(w.y, hh.y, acc);
            acc = fmaf(w.z, hh.z, acc); acc = fmaf(w.w, hh.w, acc);
        }
        const float cw = sigmoidf(acc + b2[m * D_ + d]);
        const float wv = (r ? p1 : p0) * cw;
        wf[(size_t)(m * B_ + b) * D_ + d] = wv;
        wsum += wv;
    }
    __syncthreads();  // protect red[] reuse
    float tot = wave_sum64(wsum);
    if ((t & 63) == 0) red[t >> 6] = tot;
    __syncthreads();
    if (t == 0) Ssum[m * B_ + b] = red[0] + red[1] + red[2] + red[3];
}

// ---------------------------------------------------------------------------
// Kernel 2 (pass A): first j per i, hist = 0.
//   final = 0.8*clip(t,-c,c) + 0.2*t,  t = (wf_i[b,d]/sqrt(D)) * wf_j[b,e]
// One wave owns (i,d): 8 e's/lane, H-row accumulated in 8 VGPRs over b.
// Writes attA[i,b,d] = softmax-dot (no max-sub; |final| <= ~0.5) and
// H[i,d,:] = sum_b(final)/(B*HIST).
// grid = M_*128 = 384 blocks, 256 threads (4 waves = 4 d's per block).
// ---------------------------------------------------------------------------
__global__ __launch_bounds__(256) void k_passA(
    const float* __restrict__ wf, const float* __restrict__ constraint,
    float* __restrict__ attA, float* __restrict__ Hbuf)
{
    const int ii = blockIdx.x >> 7;
    const int d = ((blockIdx.x & 127) << 2) + (threadIdx.x >> 6);
    const int lane = threadIdx.x & 63;
    const int j = (ii == 0) ? 1 : 0;          // first j != i, ascending
    const float c = constraint[ii];
    const float invscale = 0.04419417382415922f;  // 1/sqrt(512)
    const float* wfi = wf + (size_t)ii * B_ * D_;
    const float* wfj = wf + (size_t)j  * B_ * D_;
    const int e0 = lane << 2;

    float h[8];
#pragma unroll
    for (int k = 0; k < 8; ++k) h[k] = 0.f;

    for (int b = 0; b < B_; ++b) {
        const float a = wfi[b * D_ + d] * invscale;
        const float4 u0 = *(const float4*)(wfj + b * D_ + e0);
        const float4 u1 = *(const float4*)(wfj + b * D_ + 256 + e0);
        const float u[8] = {u0.x, u0.y, u0.z, u0.w, u1.x, u1.y, u1.z, u1.w};
        float sum = 0.f, dot = 0.f;
#pragma unroll
        for (int k = 0; k < 8; ++k) {
            const float tt = a * u[k];
            const float mm = fminf(fmaxf(tt, -c), c);   // clip -> v_med3
            const float f  = fmaf(0.8f, mm, 0.2f * tt);
            h[k] += f;
            const float p = __expf(f);
            sum += p;
            dot = fmaf(p, u[k], dot);
        }
#pragma unroll
        for (int o = 32; o >= 1; o >>= 1) {
            sum += __shfl_xor(sum, o, 64);
            dot += __shfl_xor(dot, o, 64);
        }
        if (lane == 0) attA[(size_t)(ii * B_ + b) * D_ + d] = dot / sum;
    }
    const float hscale = 1.f / (float)(B_ * HIST_);
    float* Hrow = Hbuf + (size_t)(ii * D_ + d) * D_;
    *(float4*)(Hrow + e0)       = make_float4(h[0]*hscale, h[1]*hscale, h[2]*hscale, h[3]*hscale);
    *(float4*)(Hrow + 256 + e0) = make_float4(h[4]*hscale, h[5]*hscale, h[6]*hscale, h[7]*hscale);
}

// ---------------------------------------------------------------------------
// Kernel 3 (pass B + combine): second j per i, hist = H[i].
//   final = 0.8*(H + clip(t-H,-c,c)) + 0.2*t
// Wave owns (d, b-chunk of 16), keeps 3 H-rows (24 VGPRs), loops b then i.
// fused[b,d] = mean_i wf_i + (1/6) * sum_pairs g_ij*(smdot_ij + mb_ij*S_j[b])
// Also writes attention_weights = softmax(scores) at out[B*D..B*D+2].
// grid = 128 * 4 = 512 blocks, 256 threads.
// ---------------------------------------------------------------------------
__global__ __launch_bounds__(256) void k_passB(
    const float* __restrict__ wf, const float* __restrict__ constraint,
    const float* __restrict__ gamma, const float* __restrict__ mbias,
    const float* __restrict__ attA, const float* __restrict__ Hbuf,
    const float* __restrict__ Ssum, float* __restrict__ out)
{
    const int dg = blockIdx.x & 127;
    const int bc = blockIdx.x >> 7;
    const int d = (dg << 2) + (threadIdx.x >> 6);
    const int lane = threadIdx.x & 63;
    const int e0 = lane << 2;
    const float invscale = 0.04419417382415922f;

    const float g01 = sigmoidf(gamma[1]), g02 = sigmoidf(gamma[2]);
    const float g10 = sigmoidf(gamma[3]), g12 = sigmoidf(gamma[5]);
    const float g20 = sigmoidf(gamma[6]), g21 = sigmoidf(gamma[7]);

    // load the three H rows for this d
    float h[3][8];
#pragma unroll
    for (int i = 0; i < 3; ++i) {
        const float* Hrow = Hbuf + (size_t)(i * D_ + d) * D_;
        const float4 a0 = *(const float4*)(Hrow + e0);
        const float4 a1 = *(const float4*)(Hrow + 256 + e0);
        h[i][0]=a0.x; h[i][1]=a0.y; h[i][2]=a0.z; h[i][3]=a0.w;
        h[i][4]=a1.x; h[i][5]=a1.y; h[i][6]=a1.z; h[i][7]=a1.w;
    }

    const int blo = bc << 4;
    for (int b = blo; b < blo + 16; ++b) {
        // u rows needed: jB = {2,2,1}
        const float4 q0 = *(const float4*)(wf + (size_t)(1 * B_ + b) * D_ + e0);
        const float4 q1 = *(const float4*)(wf + (size_t)(1 * B_ + b) * D_ + 256 + e0);
        const float u1v[8] = {q0.x,q0.y,q0.z,q0.w,q1.x,q1.y,q1.z,q1.w};
        const float4 r0 = *(const float4*)(wf + (size_t)(2 * B_ + b) * D_ + e0);
        const float4 r1 = *(const float4*)(wf + (size_t)(2 * B_ + b) * D_ + 256 + e0);
        const float u2v[8] = {r0.x,r0.y,r0.z,r0.w,r1.x,r1.y,r1.z,r1.w};

        float wfd[3], dotB[3];
#pragma unroll
        for (int i = 0; i < 3; ++i) {
            wfd[i] = wf[(size_t)(i * B_ + b) * D_ + d];
            const float a = wfd[i] * invscale;
            const float c = constraint[i];
            float sum = 0.f, dot = 0.f;
#pragma unroll
            for (int k = 0; k < 8; ++k) {
                const float uk = (i == 2) ? u1v[k] : u2v[k];
                const float tt = a * uk;
                const float df = tt - h[i][k];
                const float mm = fminf(fmaxf(df, -c), c);
                const float f  = fmaf(0.8f, h[i][k] + mm, 0.2f * tt);
                const float p = __expf(f);
                sum += p;
                dot = fmaf(p, uk, dot);
            }
#pragma unroll
            for (int o = 32; o >= 1; o >>= 1) {
                sum += __shfl_xor(sum, o, 64);
                dot += __shfl_xor(dot, o, 64);
            }
            dotB[i] = dot / sum;
        }
        if (lane == 0) {
            const float aA0 = attA[(size_t)(0 * B_ + b) * D_ + d];
            const float aA1 = attA[(size_t)(1 * B_ + b) * D_ + d];
            const float aA2 = attA[(size_t)(2 * B_ + b) * D_ + d];
            const float S0 = Ssum[b], S1 = Ssum[B_ + b], S2 = Ssum[2 * B_ + b];
            float acc = (wfd[0] + wfd[1] + wfd[2]) * (1.f / 3.f);
            float pair =
                g01 * (aA0 + mbias[1] * S1) +
                g10 * (aA1 + mbias[3] * S0) +
                g20 * (aA2 + mbias[6] * S0) +
                g02 * (dotB[0] + mbias[2] * S2) +
                g12 * (dotB[1] + mbias[5] * S2) +
                g21 * (dotB[2] + mbias[7] * S1);
            out[b * D_ + d] = fmaf(pair, 1.f / 6.f, acc);
        }
    }

    if (blockIdx.x == 0 && threadIdx.x == 0) {
        const float s0 = 0.5f * (g01 + g02);
        const float s1 = 0.5f * (g10 + g12);
        const float s2 = 0.5f * (g20 + g21);
        const float mx = fmaxf(s0, fmaxf(s1, s2));
        const float e0_ = __expf(s0 - mx), e1_ = __expf(s1 - mx), e2_ = __expf(s2 - mx);
        const float den = e0_ + e1_ + e2_;
        out[B_ * D_ + 0] = e0_ / den;
        out[B_ * D_ + 1] = e1_ / den;
        out[B_ * D_ + 2] = e2_ / den;
    }
}

// ---------------------------------------------------------------------------
extern "C" void kernel_launch(void* const* d_in, const int* in_sizes, int n_in,
                              void* d_out, int out_size, void* d_ws, size_t ws_size,
                              hipStream_t stream) {
    const float* x    = (const float*)d_in[0];
    const float* pW   = (const float*)d_in[1];
    const float* pb   = (const float*)d_in[2];
    const float* lg   = (const float*)d_in[3];
    const float* lb   = (const float*)d_in[4];
    const float* W1   = (const float*)d_in[5];
    const float* b1   = (const float*)d_in[6];
    const float* W2   = (const float*)d_in[7];
    const float* b2   = (const float*)d_in[8];
    const float* gamma= (const float*)d_in[9];
    const float* mb   = (const float*)d_in[10];
    const float* cons = (const float*)d_in[11];
    float* out = (float*)d_out;

    float* ws   = (float*)d_ws;
    float* wf   = ws;               // 3*64*512 = 98304 floats
    float* attA = ws + 98304;       // 98304 floats
    float* Ssum = ws + 196608;      // 192 floats
    float* Hbuf = ws + 196800;      // 3*512*512 = 786432 floats  (total ~3.93 MB)

    k_wf<<<dim3(M_ * B_), dim3(256), 0, stream>>>(x, pW, pb, lg, lb, W1, b1, W2, b2, wf, Ssum);
    k_passA<<<dim3(M_ * 128), dim3(256), 0, stream>>>(wf, cons, attA, Hbuf);
    k_passB<<<dim3(128 * 4), dim3(256), 0, stream>>>(wf, cons, gamma, mb, attA, Hbuf, Ssum, out);
}

// Round 2
// 209.846 us; speedup vs baseline: 1.0059x; 1.0059x over previous
//
#include <hip/hip_runtime.h>
#include <math.h>

#define M_ 3
#define B_ 64
#define D_ 512
#define H4 128     // D/4
#define HIST_ 5
#define BD (B_ * D_)        // 32768
#define INVSCALE 0.04419417382415922f   // 1/sqrt(512)

__device__ __forceinline__ float wave_sum64(float v) {
#pragma unroll
    for (int o = 32; o >= 1; o >>= 1) v += __shfl_xor(v, o, 64);
    return v;
}

__device__ __forceinline__ float sigmoidf(float x) {
    return 1.0f / (1.0f + __expf(-x));
}

// ---------------------------------------------------------------------------
// Kernel 1: per (mode, batch-row) — proj GEMV + LayerNorm + ReLU, importance
// MLP, wf = proj * sigmoid(...), S[m,b] = sum_e wf.
// 512 threads (8 waves), 1 d per thread. MLP1 split 4-way over K.
// grid = M_*B_ = 192 blocks.
// ---------------------------------------------------------------------------
__global__ __launch_bounds__(512) void k_wf(
    const float* __restrict__ x,  const float* __restrict__ pW,
    const float* __restrict__ pb, const float* __restrict__ lg,
    const float* __restrict__ lb, const float* __restrict__ W1,
    const float* __restrict__ b1, const float* __restrict__ W2,
    const float* __restrict__ b2, float* __restrict__ wf,
    float* __restrict__ Ssum)
{
    const int m = blockIdx.x >> 6;
    const int b = blockIdx.x & 63;
    const int t = threadIdx.x;           // d = t
    __shared__ __align__(16) float4 xs4[D_ / 4];
    __shared__ __align__(16) float ps[D_];
    __shared__ __align__(16) float hs[H4];
    __shared__ __align__(16) float hpart[512];
    __shared__ float red[8];

    const float* xrow = x + (size_t)(m * B_ + b) * D_;
    if (t < D_ / 4) xs4[t] = ((const float4*)xrow)[t];
    __syncthreads();

    // y[t] = x[b,:] . W[t,:] + pb[t]
    const float4* wr = (const float4*)(pW + (size_t)m * D_ * D_ + (size_t)t * D_);
    float acc = 0.f;
#pragma unroll 8
    for (int k = 0; k < D_ / 4; ++k) {
        const float4 w = wr[k], xx = xs4[k];
        acc = fmaf(w.x, xx.x, acc); acc = fmaf(w.y, xx.y, acc);
        acc = fmaf(w.z, xx.z, acc); acc = fmaf(w.w, xx.w, acc);
    }
    const float y = acc + pb[m * D_ + t];

    // LayerNorm over 512 (1 per thread, 8 waves)
    float s = wave_sum64(y);
    if ((t & 63) == 0) red[t >> 6] = s;
    __syncthreads();
    const float mean = (red[0]+red[1]+red[2]+red[3]+red[4]+red[5]+red[6]+red[7]) * (1.f / D_);
    __syncthreads();   // everyone read red before reuse
    const float v = y - mean;
    float vs = wave_sum64(v * v);
    if ((t & 63) == 0) red[t >> 6] = vs;
    __syncthreads();
    const float inv = rsqrtf((red[0]+red[1]+red[2]+red[3]+red[4]+red[5]+red[6]+red[7]) * (1.f / D_) + 1e-5f);
    const float p = fmaxf(fmaf(v * inv, lg[m * D_ + t], lb[m * D_ + t]), 0.f);
    ps[t] = p;
    __syncthreads();

    // MLP1 4-way K-split: thread t -> (r = t&127, seg = t>>7), K-range seg*128..+128
    {
        const int r = t & 127, seg = t >> 7;
        const float4* w1 = (const float4*)(W1 + ((size_t)m * H4 + r) * D_) + (seg << 5);
        const float4* pv = (const float4*)ps + (seg << 5);
        float a1 = 0.f;
#pragma unroll 8
        for (int k = 0; k < 32; ++k) {
            const float4 w = w1[k], pp = pv[k];
            a1 = fmaf(w.x, pp.x, a1); a1 = fmaf(w.y, pp.y, a1);
            a1 = fmaf(w.z, pp.z, a1); a1 = fmaf(w.w, pp.w, a1);
        }
        hpart[t] = a1;
    }
    __syncthreads();
    if (t < H4) {
        const float h = hpart[t] + hpart[t + 128] + hpart[t + 256] + hpart[t + 384]
                      + b1[m * H4 + t];
        hs[t] = fmaxf(h, 0.f);
    }
    __syncthreads();

    // MLP2: cw = sigmoid(hs . W2[t,:] + b2); wf = p * cw
    const float4* w2 = (const float4*)(W2 + ((size_t)m * D_ + t) * H4);
    const float4* hv = (const float4*)hs;
    float a2 = 0.f;
#pragma unroll 8
    for (int k = 0; k < H4 / 4; ++k) {
        const float4 w = w2[k], hh = hv[k];
        a2 = fmaf(w.x, hh.x, a2); a2 = fmaf(w.y, hh.y, a2);
        a2 = fmaf(w.z, hh.z, a2); a2 = fmaf(w.w, hh.w, a2);
    }
    const float cw = sigmoidf(a2 + b2[m * D_ + t]);
    const float wv = p * cw;
    wf[(size_t)(m * B_ + b) * D_ + t] = wv;

    __syncthreads();   // red reuse
    float tot = wave_sum64(wv);
    if ((t & 63) == 0) red[t >> 6] = tot;
    __syncthreads();
    if (t == 0)
        Ssum[m * B_ + b] = red[0]+red[1]+red[2]+red[3]+red[4]+red[5]+red[6]+red[7];
}

// ---------------------------------------------------------------------------
// Kernel 2: history, TRANSPOSED: HT[i][e][d] = sum_b(0.8*clip(t)+0.2*t)/(B*HIST),
// t = wf_i[b,d]*wf_j[b,e]/sqrt(D), j = first partner of i.
// Block owns (i, 4 e's); thread owns d = t and t+256; loop b with uniform u.
// No shuffles, no atomics. grid = 3*128 = 384 blocks, 256 threads.
// ---------------------------------------------------------------------------
__global__ __launch_bounds__(256) void k_hist(
    const float* __restrict__ wf, const float* __restrict__ constraint,
    float* __restrict__ HT)
{
    const int i  = blockIdx.x >> 7;
    const int e0 = (blockIdx.x & 127) << 2;
    const int j  = (i == 0) ? 1 : 0;
    const int t  = threadIdx.x;
    const float c = constraint[i];
    const float* wfi = wf + (size_t)i * BD;
    const float* wfj = wf + (size_t)j * BD;

    float h[4][2];
#pragma unroll
    for (int e = 0; e < 4; ++e) { h[e][0] = 0.f; h[e][1] = 0.f; }

    for (int b = 0; b < B_; ++b) {
        const float a0 = wfi[b * D_ + t]       * INVSCALE;
        const float a1 = wfi[b * D_ + t + 256] * INVSCALE;
        const float4 u4 = *(const float4*)(wfj + b * D_ + e0);   // uniform
        const float uu[4] = {u4.x, u4.y, u4.z, u4.w};
#pragma unroll
        for (int e = 0; e < 4; ++e) {
            const float t0 = a0 * uu[e];
            const float t1 = a1 * uu[e];
            const float m0 = fminf(fmaxf(t0, -c), c);
            const float m1 = fminf(fmaxf(t1, -c), c);
            h[e][0] = fmaf(0.8f, m0, fmaf(0.2f, t0, h[e][0]));
            h[e][1] = fmaf(0.8f, m1, fmaf(0.2f, t1, h[e][1]));
        }
    }
    const float hsc = 1.f / (float)(B_ * HIST_);
#pragma unroll
    for (int e = 0; e < 4; ++e) {
        float* row = HT + ((size_t)(i << 9) + e0 + e) * D_;
        row[t]       = h[e][0] * hsc;
        row[t + 256] = h[e][1] * hsc;
    }
}

// ---------------------------------------------------------------------------
// Kernel 3: both softmax-dot passes per (i,b,d), lane-per-d, uniform u, no
// shuffles. Pass A: hist=0 (first j). Pass B: hist=HT (second j), coalesced
// HT[e][d] read per e. Writes combined pair[i][b][d] =
//   gA*(dotA/sumA + mbA*S_jA) + gB*(dotB/sumB + mbB*S_jB).
// grid = 3*64*2 = 384 blocks (block = 256 d's), 256 threads.
// ---------------------------------------------------------------------------
__global__ __launch_bounds__(256) void k_passAB(
    const float* __restrict__ wf, const float* __restrict__ constraint,
    const float* __restrict__ gamma, const float* __restrict__ mbias,
    const float* __restrict__ HT, const float* __restrict__ Ssum,
    float* __restrict__ pair)
{
    const int i   = blockIdx.x >> 7;
    const int rem = blockIdx.x & 127;
    const int b   = rem >> 1;
    const int d   = ((rem & 1) << 8) + threadIdx.x;
    const int jA  = (i == 0) ? 1 : 0;
    const int jB  = (i == 2) ? 1 : 2;
    const float c = constraint[i];
    const float a = wf[(size_t)i * BD + b * D_ + d] * INVSCALE;
    const float* uAp = wf + (size_t)jA * BD + b * D_;
    const float* uBp = wf + (size_t)jB * BD + b * D_;
    const float* Hp  = HT + (size_t)(i << 9) * D_ + d;   // + e*D_

    // Pass A (hist = 0)
    float sA = 0.f, dA = 0.f;
    for (int e0 = 0; e0 < D_; e0 += 4) {
        const float4 u4 = *(const float4*)(uAp + e0);            // uniform
        const float uu[4] = {u4.x, u4.y, u4.z, u4.w};
#pragma unroll
        for (int k = 0; k < 4; ++k) {
            const float tt = a * uu[k];
            const float mm = fminf(fmaxf(tt, -c), c);
            const float f  = fmaf(0.8f, mm, 0.2f * tt);
            const float p  = __expf(f);
            sA += p;
            dA = fmaf(p, uu[k], dA);
        }
    }

    // Pass B (hist = HT[i])
    float sB = 0.f, dB = 0.f;
    for (int e0 = 0; e0 < D_; e0 += 4) {
        const float4 u4 = *(const float4*)(uBp + e0);            // uniform
        const float uu[4] = {u4.x, u4.y, u4.z, u4.w};
        float hh[4];
#pragma unroll
        for (int k = 0; k < 4; ++k) hh[k] = Hp[(size_t)(e0 + k) * D_];  // coalesced
#pragma unroll
        for (int k = 0; k < 4; ++k) {
            const float tt = a * uu[k];
            const float df = tt - hh[k];
            const float mm = fminf(fmaxf(df, -c), c);
            const float f  = fmaf(0.8f, hh[k] + mm, 0.2f * tt);
            const float p  = __expf(f);
            sB += p;
            dB = fmaf(p, uu[k], dB);
        }
    }

    const float gA = sigmoidf(gamma[i * 3 + jA]);
    const float gB = sigmoidf(gamma[i * 3 + jB]);
    const float pv = gA * (dA / sA + mbias[i * 3 + jA] * Ssum[jA * B_ + b])
                   + gB * (dB / sB + mbias[i * 3 + jB] * Ssum[jB * B_ + b]);
    pair[(size_t)i * BD + b * D_ + d] = pv;
}

// ---------------------------------------------------------------------------
// Kernel 4: combine. out[b,d] = mean_i wf_i + (1/6)*sum_i pair_i.
// Also attention_weights = softmax over mode scores. grid = 128, 256 thr.
// ---------------------------------------------------------------------------
__global__ __launch_bounds__(256) void k_combine(
    const float* __restrict__ wf, const float* __restrict__ pair,
    const float* __restrict__ gamma, float* __restrict__ out)
{
    const int g = blockIdx.x * 256 + threadIdx.x;    // 0..32767
    const float w0 = wf[g], w1 = wf[BD + g], w2 = wf[2 * BD + g];
    const float p0 = pair[g], p1 = pair[BD + g], p2 = pair[2 * BD + g];
    out[g] = fmaf(p0 + p1 + p2, 1.f / 6.f, (w0 + w1 + w2) * (1.f / 3.f));

    if (g == 0) {
        const float g01 = sigmoidf(gamma[1]), g02 = sigmoidf(gamma[2]);
        const float g10 = sigmoidf(gamma[3]), g12 = sigmoidf(gamma[5]);
        const float g20 = sigmoidf(gamma[6]), g21 = sigmoidf(gamma[7]);
        const float s0 = 0.5f * (g01 + g02);
        const float s1 = 0.5f * (g10 + g12);
        const float s2 = 0.5f * (g20 + g21);
        const float mx = fmaxf(s0, fmaxf(s1, s2));
        const float e0 = __expf(s0 - mx), e1 = __expf(s1 - mx), e2 = __expf(s2 - mx);
        const float den = e0 + e1 + e2;
        out[BD + 0] = e0 / den;
        out[BD + 1] = e1 / den;
        out[BD + 2] = e2 / den;
    }
}

// ---------------------------------------------------------------------------
extern "C" void kernel_launch(void* const* d_in, const int* in_sizes, int n_in,
                              void* d_out, int out_size, void* d_ws, size_t ws_size,
                              hipStream_t stream) {
    const float* x    = (const float*)d_in[0];
    const float* pW   = (const float*)d_in[1];
    const float* pb   = (const float*)d_in[2];
    const float* lg   = (const float*)d_in[3];
    const float* lb   = (const float*)d_in[4];
    const float* W1   = (const float*)d_in[5];
    const float* b1   = (const float*)d_in[6];
    const float* W2   = (const float*)d_in[7];
    const float* b2   = (const float*)d_in[8];
    const float* gamma= (const float*)d_in[9];
    const float* mb   = (const float*)d_in[10];
    const float* cons = (const float*)d_in[11];
    float* out = (float*)d_out;

    float* ws   = (float*)d_ws;
    float* wf   = ws;                 // 98304 floats
    float* Ssum = ws + 98304;         // 192
    float* pair = ws + 98496;         // 98304
    float* HT   = ws + 196800;        // 786432  (total ~3.93 MB, as round 1)

    k_wf     <<<dim3(M_ * B_),  dim3(512), 0, stream>>>(x, pW, pb, lg, lb, W1, b1, W2, b2, wf, Ssum);
    k_hist   <<<dim3(M_ * 128), dim3(256), 0, stream>>>(wf, cons, HT);
    k_passAB <<<dim3(M_ * 128), dim3(256), 0, stream>>>(wf, cons, gamma, mb, HT, Ssum, pair);
    k_combine<<<dim3(128),      dim3(256), 0, stream>>>(wf, pair, gamma, out);
}

// Round 3
// 161.792 us; speedup vs baseline: 1.3047x; 1.2970x over previous
//
#include <hip/hip_runtime.h>
#include <math.h>

#define M_ 3
#define B_ 64
#define D_ 512
#define H4 128     // D/4
#define HIST_ 5
#define BD (B_ * D_)        // 32768
#define INVSCALE 0.04419417382415922f   // 1/sqrt(512)
#define LOG2E 1.4426950408889634f

__device__ __forceinline__ float wave_sum64(float v) {
#pragma unroll
    for (int o = 32; o >= 1; o >>= 1) v += __shfl_xor(v, o, 64);
    return v;
}

__device__ __forceinline__ float sigmoidf(float x) {
    return 1.0f / (1.0f + __expf(-x));
}

// ---------------------------------------------------------------------------
// k_proj: partial GEMM  ypart[m,b,kq,d] = sum_{k in kq-quarter} x[m,b,k]*W[m,d,k]
// grid = 3 * 32 b-pairs * 4 kq = 384 blocks, 512 threads (thread = d).
// Each thread: 32 independent float4 W-loads (deep MLP pipelining), 2 b's.
// ---------------------------------------------------------------------------
__global__ __launch_bounds__(512) void k_proj(
    const float* __restrict__ x, const float* __restrict__ pW,
    float* __restrict__ ypart)
{
    const int m  = blockIdx.x >> 7;           // /128
    const int rem = blockIdx.x & 127;
    const int b0 = (rem >> 2) << 1;           // b-pair base
    const int kq = rem & 3;
    const int t  = threadIdx.x;               // d

    __shared__ __align__(16) float4 xs[2][32];
    if (t < 64) {
        const int r = t >> 5, c = t & 31;
        xs[r][c] = ((const float4*)(x + (size_t)(m * B_ + b0 + r) * D_ + kq * 128))[c];
    }
    __syncthreads();

    const float4* wr = (const float4*)(pW + (size_t)m * D_ * D_ + (size_t)t * D_ + kq * 128);
    float acc0 = 0.f, acc1 = 0.f;
#pragma unroll
    for (int k = 0; k < 32; ++k) {
        const float4 w = wr[k];
        const float4 a = xs[0][k];
        const float4 b = xs[1][k];
        acc0 = fmaf(w.x, a.x, acc0); acc0 = fmaf(w.y, a.y, acc0);
        acc0 = fmaf(w.z, a.z, acc0); acc0 = fmaf(w.w, a.w, acc0);
        acc1 = fmaf(w.x, b.x, acc1); acc1 = fmaf(w.y, b.y, acc1);
        acc1 = fmaf(w.z, b.z, acc1); acc1 = fmaf(w.w, b.w, acc1);
    }
    const size_t idx0 = (size_t)(m * B_ + b0) * 2048 + kq * 512 + t;
    ypart[idx0]        = acc0;
    ypart[idx0 + 2048] = acc1;
}

// ---------------------------------------------------------------------------
// k_lnmlp: per (m,b) row — sum 4 ypart quarters + pb, LayerNorm+ReLU,
// MLP1 (4-way K-split over 512 thr), MLP2, wf = p*sigmoid, Ssum.
// grid = 192 blocks, 512 threads (thread = d).
// ---------------------------------------------------------------------------
__global__ __launch_bounds__(512) void k_lnmlp(
    const float* __restrict__ ypart, const float* __restrict__ pb,
    const float* __restrict__ lg, const float* __restrict__ lb,
    const float* __restrict__ W1, const float* __restrict__ b1,
    const float* __restrict__ W2, const float* __restrict__ b2,
    float* __restrict__ wf, float* __restrict__ Ssum)
{
    const int m = blockIdx.x >> 6;
    const int b = blockIdx.x & 63;
    const int t = threadIdx.x;
    __shared__ __align__(16) float ps[D_];
    __shared__ __align__(16) float hs[H4];
    __shared__ __align__(16) float hpart[512];
    __shared__ float red[8];

    const size_t rbase = (size_t)(m * B_ + b) * 2048;
    const float y = ypart[rbase + t] + ypart[rbase + 512 + t]
                  + ypart[rbase + 1024 + t] + ypart[rbase + 1536 + t]
                  + pb[m * D_ + t];

    float s = wave_sum64(y);
    if ((t & 63) == 0) red[t >> 6] = s;
    __syncthreads();
    const float mean = (red[0]+red[1]+red[2]+red[3]+red[4]+red[5]+red[6]+red[7]) * (1.f / D_);
    __syncthreads();
    const float v = y - mean;
    float vs = wave_sum64(v * v);
    if ((t & 63) == 0) red[t >> 6] = vs;
    __syncthreads();
    const float inv = rsqrtf((red[0]+red[1]+red[2]+red[3]+red[4]+red[5]+red[6]+red[7]) * (1.f / D_) + 1e-5f);
    const float p = fmaxf(fmaf(v * inv, lg[m * D_ + t], lb[m * D_ + t]), 0.f);
    ps[t] = p;
    __syncthreads();

    // MLP1: thread -> (r = t&127, seg = t>>7), K-range seg*128..+128
    {
        const int r = t & 127, seg = t >> 7;
        const float4* w1 = (const float4*)(W1 + ((size_t)m * H4 + r) * D_) + (seg << 5);
        const float4* pv = (const float4*)ps + (seg << 5);
        float a1 = 0.f;
#pragma unroll
        for (int k = 0; k < 32; ++k) {
            const float4 w = w1[k], pp = pv[k];
            a1 = fmaf(w.x, pp.x, a1); a1 = fmaf(w.y, pp.y, a1);
            a1 = fmaf(w.z, pp.z, a1); a1 = fmaf(w.w, pp.w, a1);
        }
        hpart[t] = a1;
    }
    __syncthreads();
    if (t < H4)
        hs[t] = fmaxf(hpart[t] + hpart[t + 128] + hpart[t + 256] + hpart[t + 384]
                      + b1[m * H4 + t], 0.f);
    __syncthreads();

    // MLP2: thread t -> output d=t
    const float4* w2 = (const float4*)(W2 + ((size_t)m * D_ + t) * H4);
    const float4* hv = (const float4*)hs;
    float a2 = 0.f;
#pragma unroll
    for (int k = 0; k < H4 / 4; ++k) {
        const float4 w = w2[k], hh = hv[k];
        a2 = fmaf(w.x, hh.x, a2); a2 = fmaf(w.y, hh.y, a2);
        a2 = fmaf(w.z, hh.z, a2); a2 = fmaf(w.w, hh.w, a2);
    }
    const float cw = sigmoidf(a2 + b2[m * D_ + t]);
    const float wv = p * cw;
    wf[(size_t)(m * B_ + b) * D_ + t] = wv;

    float tot = wave_sum64(wv);
    if ((t & 63) == 0) red[t >> 6] = tot;
    __syncthreads();
    if (t == 0)
        Ssum[m * B_ + b] = red[0]+red[1]+red[2]+red[3]+red[4]+red[5]+red[6]+red[7];
}

// ---------------------------------------------------------------------------
// k_hist: HT[i][e][d] = (sum_b 0.8*clip(t)+0.2*t) * LOG2E/(B*HIST)  (pre-scaled
// for the exp2 path), t = wf_i[b,d]*wf_j[b,e]/sqrt(D), j = first partner.
// grid = 3 * 256 e-pairs = 768 blocks, 256 threads (thread = d, d+256).
// ---------------------------------------------------------------------------
__global__ __launch_bounds__(256) void k_hist(
    const float* __restrict__ wf, const float* __restrict__ constraint,
    float* __restrict__ HT)
{
    const int i  = blockIdx.x >> 8;
    const int e0 = (blockIdx.x & 255) << 1;
    const int j  = (i == 0) ? 1 : 0;
    const int t  = threadIdx.x;
    const float c = constraint[i];
    const float* wfi = wf + (size_t)i * BD;
    const float* wfj = wf + (size_t)j * BD;

    float h00 = 0.f, h01 = 0.f, h10 = 0.f, h11 = 0.f;
    for (int b = 0; b < B_; ++b) {
        const float a0 = wfi[b * D_ + t]       * INVSCALE;
        const float a1 = wfi[b * D_ + t + 256] * INVSCALE;
        const float2 u2 = *(const float2*)(wfj + b * D_ + e0);
        float tt, mm;
        tt = a0 * u2.x; mm = fminf(fmaxf(tt, -c), c); h00 = fmaf(0.8f, mm, fmaf(0.2f, tt, h00));
        tt = a1 * u2.x; mm = fminf(fmaxf(tt, -c), c); h01 = fmaf(0.8f, mm, fmaf(0.2f, tt, h01));
        tt = a0 * u2.y; mm = fminf(fmaxf(tt, -c), c); h10 = fmaf(0.8f, mm, fmaf(0.2f, tt, h10));
        tt = a1 * u2.y; mm = fminf(fmaxf(tt, -c), c); h11 = fmaf(0.8f, mm, fmaf(0.2f, tt, h11));
    }
    const float hsc = LOG2E / (float)(B_ * HIST_);
    float* r0 = HT + ((size_t)(i << 9) + e0) * D_;
    r0[t]             = h00 * hsc;
    r0[t + 256]       = h01 * hsc;
    r0[D_ + t]        = h10 * hsc;
    r0[D_ + t + 256]  = h11 * hsc;
}

// ---------------------------------------------------------------------------
// k_passAB: both softmax-dots per (i,b,d), e-split 4-way across the block's
// waves, LDS partial reduce. All exp args pre-scaled by LOG2E -> bare v_exp.
// grid = 3 * 64 * 8 d-chunks = 1536 blocks, 256 threads (64 d x 4 e-quarters).
// ---------------------------------------------------------------------------
__global__ __launch_bounds__(256) void k_passAB(
    const float* __restrict__ wf, const float* __restrict__ constraint,
    const float* __restrict__ gamma, const float* __restrict__ mbias,
    const float* __restrict__ HT, const float* __restrict__ Ssum,
    float* __restrict__ pair)
{
    const int i    = blockIdx.x >> 9;          // /512
    const int rem  = blockIdx.x & 511;
    const int b    = rem >> 3;
    const int dc   = rem & 7;
    const int t    = threadIdx.x;
    const int d    = (dc << 6) + (t & 63);
    const int esec = t >> 6;
    const int jA = (i == 0) ? 1 : 0;
    const int jB = (i == 2) ? 1 : 2;

    const float cl = constraint[i] * LOG2E;
    const float a  = wf[(size_t)i * BD + b * D_ + d] * (INVSCALE * LOG2E);
    const float* uAp = wf + (size_t)jA * BD + b * D_ + (esec << 7);
    const float* uBp = wf + (size_t)jB * BD + b * D_ + (esec << 7);
    const float* Hp  = HT + ((size_t)(i << 9) + (esec << 7)) * D_ + d;

    float sA = 0.f, dA = 0.f;
#pragma unroll 4
    for (int e = 0; e < 128; e += 4) {
        const float4 u4 = *(const float4*)(uAp + e);
        const float uu[4] = {u4.x, u4.y, u4.z, u4.w};
#pragma unroll
        for (int k = 0; k < 4; ++k) {
            const float tt = a * uu[k];
            const float mm = fminf(fmaxf(tt, -cl), cl);
            const float f  = fmaf(0.8f, mm, 0.2f * tt);
            const float p  = __builtin_amdgcn_exp2f(f);
            sA += p;
            dA = fmaf(p, uu[k], dA);
        }
    }

    float sB = 0.f, dB = 0.f;
    const float* hp = Hp;
#pragma unroll 2
    for (int e = 0; e < 128; e += 4) {
        const float4 u4 = *(const float4*)(uBp + e);
        const float uu[4] = {u4.x, u4.y, u4.z, u4.w};
        float hh[4];
#pragma unroll
        for (int k = 0; k < 4; ++k) hh[k] = hp[(size_t)k * D_];
        hp += 4 * D_;
#pragma unroll
        for (int k = 0; k < 4; ++k) {
            const float tt = a * uu[k];
            const float df = tt - hh[k];
            const float mm = fminf(fmaxf(df, -cl), cl);
            const float f  = fmaf(0.8f, hh[k] + mm, 0.2f * tt);
            const float p  = __builtin_amdgcn_exp2f(f);
            sB += p;
            dB = fmaf(p, uu[k], dB);
        }
    }

    __shared__ __align__(16) float4 part[256];
    part[t] = make_float4(sA, dA, sB, dB);
    __syncthreads();
    if (t < 64) {
        const float4 p0 = part[t], p1 = part[t + 64], p2 = part[t + 128], p3 = part[t + 192];
        const float SsA = p0.x + p1.x + p2.x + p3.x;
        const float SdA = p0.y + p1.y + p2.y + p3.y;
        const float SsB = p0.z + p1.z + p2.z + p3.z;
        const float SdB = p0.w + p1.w + p2.w + p3.w;
        const float gA = sigmoidf(gamma[i * 3 + jA]);
        const float gB = sigmoidf(gamma[i * 3 + jB]);
        const float pv = gA * (SdA / SsA + mbias[i * 3 + jA] * Ssum[jA * B_ + b])
                       + gB * (SdB / SsB + mbias[i * 3 + jB] * Ssum[jB * B_ + b]);
        pair[(size_t)i * BD + b * D_ + d] = pv;
    }
}

// ---------------------------------------------------------------------------
// k_combine: out[b,d] = mean_i wf_i + (1/6)*sum_i pair_i; plus mode softmax.
// ---------------------------------------------------------------------------
__global__ __launch_bounds__(256) void k_combine(
    const float* __restrict__ wf, const float* __restrict__ pair,
    const float* __restrict__ gamma, float* __restrict__ out)
{
    const int g = blockIdx.x * 256 + threadIdx.x;
    const float w0 = wf[g], w1 = wf[BD + g], w2 = wf[2 * BD + g];
    const float p0 = pair[g], p1 = pair[BD + g], p2 = pair[2 * BD + g];
    out[g] = fmaf(p0 + p1 + p2, 1.f / 6.f, (w0 + w1 + w2) * (1.f / 3.f));

    if (g == 0) {
        const float g01 = sigmoidf(gamma[1]), g02 = sigmoidf(gamma[2]);
        const float g10 = sigmoidf(gamma[3]), g12 = sigmoidf(gamma[5]);
        const float g20 = sigmoidf(gamma[6]), g21 = sigmoidf(gamma[7]);
        const float s0 = 0.5f * (g01 + g02);
        const float s1 = 0.5f * (g10 + g12);
        const float s2 = 0.5f * (g20 + g21);
        const float mx = fmaxf(s0, fmaxf(s1, s2));
        const float e0 = __expf(s0 - mx), e1 = __expf(s1 - mx), e2 = __expf(s2 - mx);
        const float den = e0 + e1 + e2;
        out[BD + 0] = e0 / den;
        out[BD + 1] = e1 / den;
        out[BD + 2] = e2 / den;
    }
}

// ---------------------------------------------------------------------------
extern "C" void kernel_launch(void* const* d_in, const int* in_sizes, int n_in,
                              void* d_out, int out_size, void* d_ws, size_t ws_size,
                              hipStream_t stream) {
    const float* x    = (const float*)d_in[0];
    const float* pW   = (const float*)d_in[1];
    const float* pb   = (const float*)d_in[2];
    const float* lg   = (const float*)d_in[3];
    const float* lb   = (const float*)d_in[4];
    const float* W1   = (const float*)d_in[5];
    const float* b1   = (const float*)d_in[6];
    const float* W2   = (const float*)d_in[7];
    const float* b2   = (const float*)d_in[8];
    const float* gamma= (const float*)d_in[9];
    const float* mb   = (const float*)d_in[10];
    const float* cons = (const float*)d_in[11];
    float* out = (float*)d_out;

    float* ws    = (float*)d_ws;
    float* wf    = ws;                 // 98304 floats
    float* Ssum  = ws + 98304;         // 192
    float* HT    = ws + 98496;         // 786432
    float* ypart = ws + 884928;        // 393216 (reused as `pair` after k_lnmlp)
    float* pair  = ypart;              // alias: ypart dead once k_lnmlp completes
    // total: 1278144 floats ~= 5.0 MB

    k_proj   <<<dim3(384),      dim3(512), 0, stream>>>(x, pW, ypart);
    k_lnmlp  <<<dim3(M_ * B_),  dim3(512), 0, stream>>>(ypart, pb, lg, lb, W1, b1, W2, b2, wf, Ssum);
    k_hist   <<<dim3(M_ * 256), dim3(256), 0, stream>>>(wf, cons, HT);
    k_passAB <<<dim3(M_ * 512), dim3(256), 0, stream>>>(wf, cons, gamma, mb, HT, Ssum, pair);
    k_combine<<<dim3(128),      dim3(256), 0, stream>>>(wf, pair, gamma, out);
}

// Round 4
// 155.011 us; speedup vs baseline: 1.3617x; 1.0437x over previous
//
#include <hip/hip_runtime.h>
#include <math.h>

#define M_ 3
#define B_ 64
#define D_ 512
#define H4 128     // D/4
#define HIST_ 5
#define BD (B_ * D_)        // 32768
#define INVSCALE 0.04419417382415922f   // 1/sqrt(512)
#define LOG2E 1.4426950408889634f

__device__ __forceinline__ float wave_sum64(float v) {
#pragma unroll
    for (int o = 32; o >= 1; o >>= 1) v += __shfl_xor(v, o, 64);
    return v;
}

__device__ __forceinline__ float sigmoidf(float x) {
    return 1.0f / (1.0f + __expf(-x));
}

// ---------------------------------------------------------------------------
// k_proj: partial GEMM ypart[m,b,kq,d] = sum_{k in kq} x[m,b,k]*W[m,d,k].
// grid = 3 * 4 kq * 2 dhalf * 32 bpair = 768 blocks (3/CU), 256 threads.
// Also writes attention_weights (pure function of gamma) from block 0.
// ---------------------------------------------------------------------------
__global__ __launch_bounds__(256) void k_proj(
    const float* __restrict__ x, const float* __restrict__ pW,
    const float* __restrict__ gamma, float* __restrict__ ypart,
    float* __restrict__ out)
{
    const int m    = blockIdx.x >> 8;
    const int r    = blockIdx.x & 255;
    const int kq   = r >> 6;
    const int rem2 = r & 63;
    const int dh   = rem2 >> 5;
    const int bp   = rem2 & 31;
    const int b0   = bp << 1;
    const int t    = threadIdx.x;
    const int d    = (dh << 8) + t;

    __shared__ __align__(16) float4 xs[2][32];
    if (t < 64) {
        const int rr = t >> 5, cc = t & 31;
        xs[rr][cc] = ((const float4*)(x + (size_t)(m * B_ + b0 + rr) * D_ + kq * 128))[cc];
    }
    __syncthreads();

    const float4* wr = (const float4*)(pW + (size_t)m * D_ * D_ + (size_t)d * D_ + kq * 128);
    float acc0 = 0.f, acc1 = 0.f;
#pragma unroll
    for (int k = 0; k < 32; ++k) {
        const float4 w = wr[k];
        const float4 a = xs[0][k];
        const float4 b = xs[1][k];
        acc0 = fmaf(w.x, a.x, acc0); acc0 = fmaf(w.y, a.y, acc0);
        acc0 = fmaf(w.z, a.z, acc0); acc0 = fmaf(w.w, a.w, acc0);
        acc1 = fmaf(w.x, b.x, acc1); acc1 = fmaf(w.y, b.y, acc1);
        acc1 = fmaf(w.z, b.z, acc1); acc1 = fmaf(w.w, b.w, acc1);
    }
    const size_t idx0 = (size_t)(m * B_ + b0) * 2048 + kq * 512 + d;
    ypart[idx0]        = acc0;
    ypart[idx0 + 2048] = acc1;

    if (blockIdx.x == 0 && t == 0) {
        const float g01 = sigmoidf(gamma[1]), g02 = sigmoidf(gamma[2]);
        const float g10 = sigmoidf(gamma[3]), g12 = sigmoidf(gamma[5]);
        const float g20 = sigmoidf(gamma[6]), g21 = sigmoidf(gamma[7]);
        const float s0 = 0.5f * (g01 + g02);
        const float s1 = 0.5f * (g10 + g12);
        const float s2 = 0.5f * (g20 + g21);
        const float mx = fmaxf(s0, fmaxf(s1, s2));
        const float e0 = __expf(s0 - mx), e1 = __expf(s1 - mx), e2 = __expf(s2 - mx);
        const float den = e0 + e1 + e2;
        out[BD + 0] = e0 / den;
        out[BD + 1] = e1 / den;
        out[BD + 2] = e2 / den;
    }
}

// ---------------------------------------------------------------------------
// k_lnmlp: per (m,b) row — sum 4 ypart quarters + pb, LayerNorm+ReLU,
// MLP1 (4-way K-split), MLP2, wf = p*sigmoid, Ssum. Adds wf/3 into out.
// grid = 192 blocks, 512 threads (thread = d).
// ---------------------------------------------------------------------------
__global__ __launch_bounds__(512) void k_lnmlp(
    const float* __restrict__ ypart, const float* __restrict__ pb,
    const float* __restrict__ lg, const float* __restrict__ lb,
    const float* __restrict__ W1, const float* __restrict__ b1,
    const float* __restrict__ W2, const float* __restrict__ b2,
    float* __restrict__ wf, float* __restrict__ Ssum,
    float* __restrict__ out)
{
    const int m = blockIdx.x >> 6;
    const int b = blockIdx.x & 63;
    const int t = threadIdx.x;
    __shared__ __align__(16) float ps[D_];
    __shared__ __align__(16) float hs[H4];
    __shared__ __align__(16) float hpart[512];
    __shared__ float red[8];

    const size_t rbase = (size_t)(m * B_ + b) * 2048;
    const float y = ypart[rbase + t] + ypart[rbase + 512 + t]
                  + ypart[rbase + 1024 + t] + ypart[rbase + 1536 + t]
                  + pb[m * D_ + t];

    float s = wave_sum64(y);
    if ((t & 63) == 0) red[t >> 6] = s;
    __syncthreads();
    const float mean = (red[0]+red[1]+red[2]+red[3]+red[4]+red[5]+red[6]+red[7]) * (1.f / D_);
    __syncthreads();
    const float v = y - mean;
    float vs = wave_sum64(v * v);
    if ((t & 63) == 0) red[t >> 6] = vs;
    __syncthreads();
    const float inv = rsqrtf((red[0]+red[1]+red[2]+red[3]+red[4]+red[5]+red[6]+red[7]) * (1.f / D_) + 1e-5f);
    const float p = fmaxf(fmaf(v * inv, lg[m * D_ + t], lb[m * D_ + t]), 0.f);
    ps[t] = p;
    __syncthreads();

    // MLP1: thread -> (r = t&127, seg = t>>7)
    {
        const int r = t & 127, seg = t >> 7;
        const float4* w1 = (const float4*)(W1 + ((size_t)m * H4 + r) * D_) + (seg << 5);
        const float4* pv = (const float4*)ps + (seg << 5);
        float a1 = 0.f;
#pragma unroll
        for (int k = 0; k < 32; ++k) {
            const float4 w = w1[k], pp = pv[k];
            a1 = fmaf(w.x, pp.x, a1); a1 = fmaf(w.y, pp.y, a1);
            a1 = fmaf(w.z, pp.z, a1); a1 = fmaf(w.w, pp.w, a1);
        }
        hpart[t] = a1;
    }
    __syncthreads();
    if (t < H4)
        hs[t] = fmaxf(hpart[t] + hpart[t + 128] + hpart[t + 256] + hpart[t + 384]
                      + b1[m * H4 + t], 0.f);
    __syncthreads();

    // MLP2
    const float4* w2 = (const float4*)(W2 + ((size_t)m * D_ + t) * H4);
    const float4* hv = (const float4*)hs;
    float a2 = 0.f;
#pragma unroll
    for (int k = 0; k < H4 / 4; ++k) {
        const float4 w = w2[k], hh = hv[k];
        a2 = fmaf(w.x, hh.x, a2); a2 = fmaf(w.y, hh.y, a2);
        a2 = fmaf(w.z, hh.z, a2); a2 = fmaf(w.w, hh.w, a2);
    }
    const float cw = sigmoidf(a2 + b2[m * D_ + t]);
    const float wv = p * cw;
    wf[(size_t)(m * B_ + b) * D_ + t] = wv;
    atomicAdd(&out[b * D_ + t], wv * (1.f / 3.f));

    float tot = wave_sum64(wv);
    if ((t & 63) == 0) red[t >> 6] = tot;
    __syncthreads();
    if (t == 0)
        Ssum[m * B_ + b] = red[0]+red[1]+red[2]+red[3]+red[4]+red[5]+red[6]+red[7];
}

// ---------------------------------------------------------------------------
// k_hist: HT[i][e][d] = (sum_b 0.8*clip(t)+0.2*t) * LOG2E/(B*HIST), transposed,
// pre-scaled for exp2. grid = 3 * 256 e-pairs = 768 blocks, 256 threads.
// ---------------------------------------------------------------------------
__global__ __launch_bounds__(256) void k_hist(
    const float* __restrict__ wf, const float* __restrict__ constraint,
    float* __restrict__ HT)
{
    const int i  = blockIdx.x >> 8;
    const int e0 = (blockIdx.x & 255) << 1;
    const int j  = (i == 0) ? 1 : 0;
    const int t  = threadIdx.x;
    const float c = constraint[i];
    const float* wfi = wf + (size_t)i * BD;
    const float* wfj = wf + (size_t)j * BD;

    float h00 = 0.f, h01 = 0.f, h10 = 0.f, h11 = 0.f;
#pragma unroll 4
    for (int b = 0; b < B_; ++b) {
        const float a0 = wfi[b * D_ + t]       * INVSCALE;
        const float a1 = wfi[b * D_ + t + 256] * INVSCALE;
        const float2 u2 = *(const float2*)(wfj + b * D_ + e0);
        float tt, mm;
        tt = a0 * u2.x; mm = fminf(fmaxf(tt, -c), c); h00 = fmaf(0.8f, mm, fmaf(0.2f, tt, h00));
        tt = a1 * u2.x; mm = fminf(fmaxf(tt, -c), c); h01 = fmaf(0.8f, mm, fmaf(0.2f, tt, h01));
        tt = a0 * u2.y; mm = fminf(fmaxf(tt, -c), c); h10 = fmaf(0.8f, mm, fmaf(0.2f, tt, h10));
        tt = a1 * u2.y; mm = fminf(fmaxf(tt, -c), c); h11 = fmaf(0.8f, mm, fmaf(0.2f, tt, h11));
    }
    const float hsc = LOG2E / (float)(B_ * HIST_);
    float* r0 = HT + ((size_t)(i << 9) + e0) * D_;
    r0[t]             = h00 * hsc;
    r0[t + 256]       = h01 * hsc;
    r0[D_ + t]        = h10 * hsc;
    r0[D_ + t + 256]  = h11 * hsc;
}

// ---------------------------------------------------------------------------
// k_passAB: both softmax-dots per (i,b,d), e-split 8-way across the block,
// LDS reduce, atomicAdd result/6 into out. exp args pre-scaled by LOG2E.
// grid = 3 * 64 b * 16 d-chunks = 3072 blocks (12/CU), 256 thr (32 d x 8 e).
// ---------------------------------------------------------------------------
__global__ __launch_bounds__(256) void k_passAB(
    const float* __restrict__ wf, const float* __restrict__ constraint,
    const float* __restrict__ gamma, const float* __restrict__ mbias,
    const float* __restrict__ HT, const float* __restrict__ Ssum,
    float* __restrict__ out)
{
    const int i    = blockIdx.x >> 10;
    const int rem  = blockIdx.x & 1023;
    const int b    = rem >> 4;
    const int dc   = rem & 15;
    const int t    = threadIdx.x;
    const int d    = (dc << 5) + (t & 31);
    const int esec = t >> 5;                 // 0..7, 64 e's each
    const int jA = (i == 0) ? 1 : 0;
    const int jB = (i == 2) ? 1 : 2;

    const float cl = constraint[i] * LOG2E;
    const float a  = wf[(size_t)i * BD + b * D_ + d] * (INVSCALE * LOG2E);
    const float* uAp = wf + (size_t)jA * BD + b * D_ + (esec << 6);
    const float* uBp = wf + (size_t)jB * BD + b * D_ + (esec << 6);
    const float* Hp  = HT + ((size_t)(i << 9) + (esec << 6)) * D_ + d;

    float sA = 0.f, dA = 0.f;
#pragma unroll 4
    for (int e = 0; e < 64; e += 4) {
        const float4 u4 = *(const float4*)(uAp + e);
        const float uu[4] = {u4.x, u4.y, u4.z, u4.w};
#pragma unroll
        for (int k = 0; k < 4; ++k) {
            const float tt = a * uu[k];
            const float mm = fminf(fmaxf(tt, -cl), cl);
            const float f  = fmaf(0.8f, mm, 0.2f * tt);
            const float p  = __builtin_amdgcn_exp2f(f);
            sA += p;
            dA = fmaf(p, uu[k], dA);
        }
    }

    float sB = 0.f, dB = 0.f;
    const float* hp = Hp;
#pragma unroll 4
    for (int e = 0; e < 64; e += 4) {
        const float4 u4 = *(const float4*)(uBp + e);
        const float uu[4] = {u4.x, u4.y, u4.z, u4.w};
        float hh[4];
#pragma unroll
        for (int k = 0; k < 4; ++k) hh[k] = hp[(size_t)k * D_];
        hp += 4 * D_;
#pragma unroll
        for (int k = 0; k < 4; ++k) {
            const float tt = a * uu[k];
            const float df = tt - hh[k];
            const float mm = fminf(fmaxf(df, -cl), cl);
            const float f  = fmaf(0.8f, hh[k] + mm, 0.2f * tt);
            const float p  = __builtin_amdgcn_exp2f(f);
            sB += p;
            dB = fmaf(p, uu[k], dB);
        }
    }

    __shared__ __align__(16) float4 part[256];
    part[t] = make_float4(sA, dA, sB, dB);
    __syncthreads();
    if (t < 32) {
        float SsA = 0.f, SdA = 0.f, SsB = 0.f, SdB = 0.f;
#pragma unroll
        for (int k = 0; k < 8; ++k) {
            const float4 pp = part[t + (k << 5)];
            SsA += pp.x; SdA += pp.y; SsB += pp.z; SdB += pp.w;
        }
        const float gA = sigmoidf(gamma[i * 3 + jA]);
        const float gB = sigmoidf(gamma[i * 3 + jB]);
        const float pv = gA * (SdA / SsA + mbias[i * 3 + jA] * Ssum[jA * B_ + b])
                       + gB * (SdB / SsB + mbias[i * 3 + jB] * Ssum[jB * B_ + b]);
        atomicAdd(&out[b * D_ + d], pv * (1.f / 6.f));
    }
}

// ---------------------------------------------------------------------------
extern "C" void kernel_launch(void* const* d_in, const int* in_sizes, int n_in,
                              void* d_out, int out_size, void* d_ws, size_t ws_size,
                              hipStream_t stream) {
    const float* x    = (const float*)d_in[0];
    const float* pW   = (const float*)d_in[1];
    const float* pb   = (const float*)d_in[2];
    const float* lg   = (const float*)d_in[3];
    const float* lb   = (const float*)d_in[4];
    const float* W1   = (const float*)d_in[5];
    const float* b1   = (const float*)d_in[6];
    const float* W2   = (const float*)d_in[7];
    const float* b2   = (const float*)d_in[8];
    const float* gamma= (const float*)d_in[9];
    const float* mb   = (const float*)d_in[10];
    const float* cons = (const float*)d_in[11];
    float* out = (float*)d_out;

    float* ws    = (float*)d_ws;
    float* wf    = ws;                 // 98304 floats
    float* Ssum  = ws + 98304;         // 192
    float* HT    = ws + 98496;         // 786432
    float* ypart = ws + 884928;        // 393216   (total ~4.9 MB)

    // out[0..BD) accumulated via atomics — zero it first (capture-safe).
    hipMemsetAsync(out, 0, (size_t)BD * sizeof(float), stream);

    k_proj  <<<dim3(768),       dim3(256), 0, stream>>>(x, pW, gamma, ypart, out);
    k_lnmlp <<<dim3(M_ * B_),   dim3(512), 0, stream>>>(ypart, pb, lg, lb, W1, b1, W2, b2, wf, Ssum, out);
    k_hist  <<<dim3(M_ * 256),  dim3(256), 0, stream>>>(wf, cons, HT);
    k_passAB<<<dim3(M_ * 1024), dim3(256), 0, stream>>>(wf, cons, gamma, mb, HT, Ssum, out);
}